// Round 10
// baseline (110.397 us; speedup 1.0000x reference)
//
#include <hip/hip_runtime.h>
#include <hip/hip_bf16.h>

// SocialPooling round 18: row-split occupancy kernel, spill-free this time.
// Unified theory: R11-R16's phantom traffic + ~20us overhead = forced spill.
// 1024-thr blocks ALWAYS cap at 128 regs (16 waves/block => 4 waves/SIMD);
// R12's live set was ~128 exactly (short8 = 4 VGPRs) => ~8 spilled regs =
// 32B/thread = the exact phantom WRITE excess.
// Fix: pt-pair restructure cuts inner-loop demand to ~108 regs:
//   per af-pair: pt2[2] (8 regs) accumulated with hm loaded 1 frag at a time
//   (4 regs), pack af, fire 4 acc-MFMAs, next pair. Order-identical numerics.
// (512,4) now forces 2 blocks/CU = 4 waves/SIMD with NO spill.
// Epilogue/finish = verified R12 (sharded atomics, slim finish).
// absmax expected 0.03125.

#define NSEQ 256
#define NTOT (NSEQ*64)
#define EPSV 1e-5f

typedef __attribute__((ext_vector_type(8))) short short8;
typedef __attribute__((ext_vector_type(4))) float f32x4;
typedef unsigned short ushort_t;

__device__ __forceinline__ ushort_t f2b(float f) {
    __hip_bfloat16 h = __float2bfloat16(f);                 // RNE
    return *reinterpret_cast<ushort_t*>(&h);
}
__device__ __forceinline__ int kperm(int k) {               // slot -> source kf
    return ((k >> 5)*2 + ((k & 7) >> 2))*16 + ((k >> 3) & 3)*4 + (k & 3);
}

// ---------------- K0: W -> bf16 Wt'[g][col][slot] = W[g*64 + pi(slot)][col] ----------------
// also zeroes statbuf[16][128] (runs before sp_main in-stream => ordering guaranteed)
__global__ __launch_bounds__(256) void sp_transpose(
    const float* __restrict__ W, short* __restrict__ Wt, float* __restrict__ statbuf)
{
    __shared__ __align__(16) float Tl[64*68];
    const int b = blockIdx.x, tid = threadIdx.x;
    if (b == 0) {
        #pragma unroll
        for (int q = 0; q < 8; ++q) statbuf[q*256 + tid] = 0.0f;
    }
    const float* wg = W + (size_t)b*4096;
    for (int m = 0; m < 4; ++m) {
        int c = m*256 + tid;
        int k = c >> 4, t0 = (c & 15)*4;
        *(f32x4*)(Tl + k*68 + t0) = *(const f32x4*)(wg + k*64 + t0);
    }
    __syncthreads();
    for (int m = 0; m < 2; ++m) {
        int q = m*256 + tid;
        int col = q >> 3, k0 = (q & 7)*8;
        short8 o;
        #pragma unroll
        for (int i2 = 0; i2 < 8; ++i2)
            o[i2] = (short)f2b(Tl[kperm(k0 + i2)*68 + col]);
        *(short8*)(Wt + ((size_t)(b*64 + col)*64 + k0)) = o;
    }
}

// ---------------- K1: main (2 blocks per sequence; block owns 32 output rows) ----------------
// LDS staging: Ht u16[64][72]@0 9216, cm[32][64]@9216 2048, pos@11264 512,
//              Hf short8[8][64]@11776 8192  -> 19968
// epilogue:    Xs0 f32[32][68]@0 8704, Xs1@8704 8704, red[2][4][64]@17408 2048 -> 19456
#define SM_CM   9216
#define SM_POS  11264
#define SM_HF   11776
#define SM_XS1  8704
#define SM_RED  17408
#define SM_TOT  19968

__global__ __launch_bounds__(512, 4) void sp_main(
    const float* __restrict__ h, const float* __restrict__ pos,
    const short* __restrict__ Wt, const float* __restrict__ bvec,
    float* __restrict__ X, float* __restrict__ statbuf)
{
    __shared__ __align__(16) char smem[SM_TOT];
    ushort_t*      Ht = (ushort_t*)(smem);
    unsigned char* cm = (unsigned char*)(smem + SM_CM);
    float*         px = (float*)(smem + SM_POS);
    float*         py = px + 64;
    short*         Hf = (short*)(smem + SM_HF);   // [frag 0..7][lane] short8

    const int b    = blockIdx.x;
    const int seq  = b >> 1;            // sequence
    const int row0 = (b & 1) * 32;      // this block's output-row half
    const int base = seq * 64;
    const int tid  = threadIdx.x;
    const int lane = tid & 63, w = tid >> 6;      // 8 waves; wave owns cells w*8..w*8+7
    const int ln15 = lane & 15, ln4 = lane >> 4;
    const int xph  = (b >> 3) & 7;      // stagger phase: varies WITHIN an XCD

    if (tid < 64) { px[tid] = pos[(base + tid)*2]; py[tid] = pos[(base + tid)*2 + 1]; }
    // stage H transposed (full sequence): Ht[kf][j] = bf16(H[j][kf])
    for (int m = 0; m < 2; ++m) {
        int c = m*512 + tid;
        int j = c >> 4, t0 = (c & 15)*4;
        f32x4 v = *(const f32x4*)(h + (size_t)(base + j)*64 + t0);
        #pragma unroll
        for (int u = 0; u < 4; ++u) Ht[(t0 + u)*72 + j] = f2b(v[u]);
    }
    __syncthreads();

    // cellmap for THIS half's ego rows: cm[il][j], il = 0..31 (global i = row0+il)
    for (int m = 0; m < 4; ++m) {
        int p = m*512 + tid;
        int il = p >> 6, j = p & 63;
        int i  = row0 + il;
        unsigned char val = 255;
        if (i != j) {
            float ax = px[i], ay = py[i], ox = px[j], oy = py[j];
            float tlx = ax - 1.0f, tly = ay + 1.0f, brx = ax + 1.0f, bry = ay - 1.0f;
            bool oob = (ox >= brx) | (ox <= tlx) | (oy >= tly) | (oy <= bry);
            if (!oob) {
                int g = (int)(floorf((ox - tlx)*4.0f) + floorf((tly - oy)*4.0f)*8.0f);
                g = g < 0 ? 0 : (g > 63 ? 63 : g);
                val = (unsigned char)g;
            }
        }
        cm[il*64 + j] = val;
    }
    // build Hf: wave-invariant A-frags, laid out lane-contiguous (conflict-free b128)
    if (tid < 64) {
        #pragma unroll
        for (int f = 0; f < 8; ++f) {
            int mt = f >> 1, kt2 = f & 1;
            short8 v = *(const short8*)(Ht + (mt*16 + ln15)*72 + kt2*32 + ln4*8);
            *(short8*)(Hf + (f*64 + lane)*8) = v;
        }
    }
    __syncthreads();

    // one-hot precompute: ohw[rt][kt][half] byte u = 1<<(cm_byte - w*8) if in-range.
    unsigned ohw[2][2][2];
    {
        const unsigned w8 = (unsigned)(w * 8);
        #pragma unroll
        for (int rt = 0; rt < 2; ++rt)
            #pragma unroll
            for (int kt = 0; kt < 2; ++kt) {
                const unsigned* cp = (const unsigned*)(cm + (rt*16 + ln15)*64 + kt*32 + ln4*8);
                #pragma unroll
                for (int half = 0; half < 2; ++half) {
                    unsigned cw = cp[half], oh = 0u;
                    #pragma unroll
                    for (int u = 0; u < 4; ++u) {
                        unsigned d = ((cw >> (8*u)) & 255u) - w8;   // wraps huge if byte<w8
                        if (d < 8u) oh |= (1u << d) << (8*u);
                    }
                    ohw[rt][kt][half] = oh;
                }
            }
    }

    f32x4 acc[2][4];                    // [rt][nt]
    #pragma unroll
    for (int rt = 0; rt < 2; ++rt)
        #pragma unroll
        for (int nt = 0; nt < 4; ++nt) acc[rt][nt] = (f32x4){0.f,0.f,0.f,0.f};

    // cell loop; pt-pair structure keeps live regs ~108 (no spill at 128 cap)
    for (int cc = 0; cc < 8; ++cc) {
        const int c2 = (cc + xph) & 7;              // wave-uniform
        const int g  = w*8 + c2;
        const short* wgp = Wt + (size_t)g*4096;
        short8 bw[2][4];
        #pragma unroll
        for (int kt = 0; kt < 2; ++kt)
            #pragma unroll
            for (int nt = 0; nt < 4; ++nt)
                bw[kt][nt] = *(const short8*)(wgp + (nt*16 + ln15)*64 + kt*32 + ln4*8);

        #pragma unroll
        for (int rt = 0; rt < 2; ++rt) {
            short8 sf[2];
            #pragma unroll
            for (int kt = 0; kt < 2; ++kt) {
                unsigned t0 = (ohw[rt][kt][0] >> c2) & 0x01010101u;  // e0..e3 flags
                unsigned t1 = (ohw[rt][kt][1] >> c2) & 0x01010101u;  // e4..e7 flags
                union { unsigned u[4]; short8 s; } sfu;
                sfu.u[0] = ((t0 & 1u)          | ((t0 << 8) & 0x10000u)) * 0x3F80u; // e0,e1
                sfu.u[1] = (((t0 >> 16) & 1u)  | ((t0 >> 8) & 0x10000u)) * 0x3F80u; // e2,e3
                sfu.u[2] = ((t1 & 1u)          | ((t1 << 8) & 0x10000u)) * 0x3F80u; // e4,e5
                sfu.u[3] = (((t1 >> 16) & 1u)  | ((t1 >> 8) & 0x10000u)) * 0x3F80u; // e6,e7
                sf[kt] = sfu.s;
            }
            // af-pair ktp: pt2 = {pt[2ktp], pt[2ktp+1]}, hm loaded 1 frag at a time
            #pragma unroll
            for (int ktp = 0; ktp < 2; ++ktp) {
                f32x4 pt2[2];
                pt2[0] = (f32x4){0.f,0.f,0.f,0.f};
                pt2[1] = (f32x4){0.f,0.f,0.f,0.f};
                #pragma unroll
                for (int mtp = 0; mtp < 2; ++mtp) {
                    const int mt = ktp*2 + mtp;
                    #pragma unroll
                    for (int kt2 = 0; kt2 < 2; ++kt2) {
                        short8 hm = *(const short8*)(Hf + ((mt*2 + kt2)*64 + lane)*8);
                        pt2[mtp] = __builtin_amdgcn_mfma_f32_16x16x32_bf16(hm, sf[kt2], pt2[mtp], 0, 0, 0);
                    }
                }
                short8 af;
                #pragma unroll
                for (int r = 0; r < 4; ++r) {
                    af[r]     = (short)f2b(pt2[0][r]);
                    af[4 + r] = (short)f2b(pt2[1][r]);
                }
                #pragma unroll
                for (int nt = 0; nt < 4; ++nt)
                    acc[rt][nt] = __builtin_amdgcn_mfma_f32_16x16x32_bf16(af, bw[ktp][nt], acc[rt][nt], 0, 0, 0);
            }
        }
    }
    __syncthreads();                                 // all cell-loop LDS reads done

    // 4-step two-buffer combine: waves 0-3 -> Xs0, waves 4-7 -> Xs1 (parallel)
    float* Xs0 = (float*)smem;
    float* Xs1 = (float*)(smem + SM_XS1);
    for (int step = 0; step < 4; ++step) {
        if ((w & 3) == step) {
            float* Xs = (w < 4) ? Xs0 : Xs1;
            #pragma unroll
            for (int rt = 0; rt < 2; ++rt)
                #pragma unroll
                for (int nt = 0; nt < 4; ++nt)
                    #pragma unroll
                    for (int r = 0; r < 4; ++r) {
                        int row = rt*16 + ln4*4 + r; // local row 0..31
                        int col = nt*16 + ln15;
                        if (step == 0) Xs[row*68 + col]  = acc[rt][nt][r];
                        else           Xs[row*68 + col] += acc[rt][nt][r];
                    }
        }
        __syncthreads();
    }

    // write X + bias (one f32x4 per thread): 512 threads x 4 floats = 32x64
    {
        const int lr = tid >> 4, c0 = (tid & 15)*4;
        float* xg = X + (size_t)(base + row0 + lr)*64 + c0;
        f32x4 v;
        #pragma unroll
        for (int u = 0; u < 4; ++u) {
            int o = lr*68 + c0 + u;
            v[u] = Xs0[o] + Xs1[o] + bvec[c0 + u];
        }
        *(f32x4*)xg = v;
    }

    // per-block column sum / sumsq (with bias) over 32 rows -> sharded atomic stats
    {
        float* red1 = (float*)(smem + SM_RED);       // [4][64]
        float* red2 = red1 + 256;
        if (tid < 256) {
            int col = tid & 63, rg = tid >> 6;
            float bc = bvec[col], s1 = 0.f, s2 = 0.f;
            for (int ii = 0; ii < 8; ++ii) {
                int o = (rg*8 + ii)*68 + col;
                float xv = Xs0[o] + Xs1[o] + bc;
                s1 += xv; s2 += xv*xv;
            }
            red1[rg*64 + col] = s1;
            red2[rg*64 + col] = s2;
        }
        __syncthreads();
        if (tid < 128) {
            int hs = tid >> 6, c2 = tid & 63;
            const float* r0 = hs ? red2 : red1;
            float v = r0[c2] + r0[64 + c2] + r0[128 + c2] + r0[192 + c2];
            atomicAdd(statbuf + (b & 15)*128 + tid, v);  // 16-way sharded
        }
    }
}

// ---------------- K2: read sharded stats + normalize + ReLU ----------------
__global__ __launch_bounds__(256) void sp_finish(
    float* __restrict__ X, const float* __restrict__ statbuf,
    const float* __restrict__ gamma, const float* __restrict__ beta)
{
    __shared__ float scale[64], shift[64];
    const int b = blockIdx.x, tid = threadIdx.x;

    if (tid < 64) {
        const float inv_n = 1.0f / (float)NTOT;
        float s1 = 0.f, s2 = 0.f;
        #pragma unroll
        for (int s = 0; s < 16; ++s) {
            s1 += statbuf[s*128 + tid];
            s2 += statbuf[s*128 + 64 + tid];
        }
        float mu  = s1 * inv_n;
        float var = s2 * inv_n - mu*mu;
        float sc  = gamma[tid] / sqrtf(var + EPSV);
        scale[tid] = sc;
        shift[tid] = beta[tid] - mu*sc;
    }
    __syncthreads();
    #pragma unroll
    for (int q = 0; q < 4; ++q) {
        size_t idx4 = (size_t)b*1024 + q*256 + tid;  // f32x4 units
        f32x4 v = ((f32x4*)X)[idx4];
        int c0 = ((int)idx4*4) & 63;
        #pragma unroll
        for (int u = 0; u < 4; ++u)
            v[u] = fmaxf(v[u]*scale[c0 + u] + shift[c0 + u], 0.0f);
        ((f32x4*)X)[idx4] = v;
    }
}

extern "C" void kernel_launch(void* const* d_in, const int* in_sizes, int n_in,
                              void* d_out, int out_size, void* d_ws, size_t ws_size,
                              hipStream_t stream)
{
    const float* h     = (const float*)d_in[0];
    // d_in[1] seq_start_end: provably uniform (reference only uses N//nseq)
    const float* pos   = (const float*)d_in[2];
    const float* W     = (const float*)d_in[3];
    const float* bvec  = (const float*)d_in[4];
    const float* gamma = (const float*)d_in[5];
    const float* beta  = (const float*)d_in[6];

    float* X       = (float*)d_out;
    short* Wt      = (short*)d_ws;                   // 512 KB bf16 W' (k-permuted)
    float* statbuf = (float*)((char*)d_ws + 524288); // 16*128 floats: sharded stats

    sp_transpose<<<64,      256, 0, stream>>>(W, Wt, statbuf);
    sp_main     <<<NSEQ*2,  512, 0, stream>>>(h, pos, Wt, bvec, X, statbuf);
    sp_finish   <<<NSEQ,    256, 0, stream>>>(X, statbuf, gamma, beta);
}

// Round 11
// 96.367 us; speedup vs baseline: 1.1456x; 1.1456x over previous
//
#include <hip/hip_runtime.h>
#include <hip/hip_bf16.h>

// SocialPooling round 19: R17 (best, 96.6us) + one-hot sf build in the hot loop.
//  - Structure = R8/R17 verbatim: grid 256 x 512 thr, hf2 register hoist,
//    bwA/bwB double-buffered Wt prefetch, (512,2), sharded atomic stats,
//    slim finish. Occupancy track abandoned: every >20%-occupancy variant
//    (R11-R14, R18) was slower per-dispatch AND dirtier in traffic.
//  - Only change: cmv per-element cmp/select masks (~128 VALU/cell) -> ohw
//    one-hot bit-extract (~20 bit-ops/cell). Bit trick verified R10/R12-R18;
//    register count identical (ohw 16 = cmv 16).
// Numerics identical: absmax expected 0.03125.

#define NSEQ 256
#define NTOT (NSEQ*64)
#define EPSV 1e-5f

typedef __attribute__((ext_vector_type(8))) short short8;
typedef __attribute__((ext_vector_type(4))) float f32x4;
typedef unsigned short ushort_t;

__device__ __forceinline__ ushort_t f2b(float f) {
    __hip_bfloat16 h = __float2bfloat16(f);                 // RNE
    return *reinterpret_cast<ushort_t*>(&h);
}
__device__ __forceinline__ int kperm(int k) {               // slot -> source kf
    return ((k >> 5)*2 + ((k & 7) >> 2))*16 + ((k >> 3) & 3)*4 + (k & 3);
}

// ---------------- K0: W -> bf16 Wt'[g][col][slot] = W[g*64 + pi(slot)][col] ----------------
// also zeroes statbuf[16][128] (runs before sp_main in-stream => ordering guaranteed)
__global__ __launch_bounds__(256) void sp_transpose(
    const float* __restrict__ W, short* __restrict__ Wt, float* __restrict__ statbuf)
{
    __shared__ __align__(16) float Tl[64*68];
    const int b = blockIdx.x, tid = threadIdx.x;
    if (b == 0) {
        #pragma unroll
        for (int q = 0; q < 8; ++q) statbuf[q*256 + tid] = 0.0f;
    }
    const float* wg = W + (size_t)b*4096;
    for (int m = 0; m < 4; ++m) {
        int c = m*256 + tid;
        int k = c >> 4, t0 = (c & 15)*4;
        *(f32x4*)(Tl + k*68 + t0) = *(const f32x4*)(wg + k*64 + t0);
    }
    __syncthreads();
    for (int m = 0; m < 2; ++m) {
        int q = m*256 + tid;
        int col = q >> 3, k0 = (q & 7)*8;
        short8 o;
        #pragma unroll
        for (int i2 = 0; i2 < 8; ++i2)
            o[i2] = (short)f2b(Tl[kperm(k0 + i2)*68 + col]);
        *(short8*)(Wt + ((size_t)(b*64 + col)*64 + k0)) = o;
    }
}

// ---------------- K1: main (R8/R17 structure: grid 256 x 512 thr, 8 waves) ----------------
// LDS: staging {Ht u16[64][72]@0 9216, cm@9216 4096, pos@13312 512} (aliased by)
//      epilogue {Xs0 f32[64][68]@0, Xs1@17408, red[2][4][64]@34816} tot 36864
#define SM_CM   9216
#define SM_POS  13312
#define SM_XS1  17408
#define SM_RED  34816
#define SM_TOT  36864

__global__ __launch_bounds__(512, 2) void sp_main(
    const float* __restrict__ h, const float* __restrict__ pos,
    const short* __restrict__ Wt, const float* __restrict__ bvec,
    float* __restrict__ X, float* __restrict__ statbuf)
{
    __shared__ __align__(16) char smem[SM_TOT];
    ushort_t*      Ht = (ushort_t*)(smem);
    unsigned char* cm = (unsigned char*)(smem + SM_CM);
    float*         px = (float*)(smem + SM_POS);
    float*         py = px + 64;

    const int b    = blockIdx.x;        // sequence
    const int base = b * 64;
    const int tid  = threadIdx.x;
    const int lane = tid & 63, w = tid >> 6;      // 8 waves; wave owns cells w*8..w*8+7
    const int ln15 = lane & 15, ln4 = lane >> 4;
    const int xph  = (b >> 3) & 7;      // stagger phase: varies WITHIN an XCD

    if (tid < 64) { px[tid] = pos[(base + tid)*2]; py[tid] = pos[(base + tid)*2 + 1]; }
    // stage H transposed: Ht[kf][j] = bf16(H[j][kf])
    for (int m = 0; m < 2; ++m) {
        int c = m*512 + tid;
        int j = c >> 4, t0 = (c & 15)*4;
        f32x4 v = *(const f32x4*)(h + (size_t)(base + j)*64 + t0);
        #pragma unroll
        for (int u = 0; u < 4; ++u) Ht[(t0 + u)*72 + j] = f2b(v[u]);
    }
    __syncthreads();

    // cellmap: cm[i][j] = cell 0..63 if valid pair else 255 (verified R1..R18)
    for (int m = 0; m < 8; ++m) {
        int p = m*512 + tid;
        int i = p >> 6, j = p & 63;
        unsigned char val = 255;
        if (i != j) {
            float ax = px[i], ay = py[i], ox = px[j], oy = py[j];
            float tlx = ax - 1.0f, tly = ay + 1.0f, brx = ax + 1.0f, bry = ay - 1.0f;
            bool oob = (ox >= brx) | (ox <= tlx) | (oy >= tly) | (oy <= bry);
            if (!oob) {
                int g = (int)(floorf((ox - tlx)*4.0f) + floorf((tly - oy)*4.0f)*8.0f);
                g = g < 0 ? 0 : (g > 63 ? 63 : g);
                val = (unsigned char)g;
            }
        }
        cm[i*64 + j] = val;
    }
    __syncthreads();

    // hoist GEMM1' A-frags (H^T rows)
    short8 hf2[4][2];
    #pragma unroll
    for (int mt = 0; mt < 4; ++mt)
        #pragma unroll
        for (int kt2 = 0; kt2 < 2; ++kt2)
            hf2[mt][kt2] = *(const short8*)(Ht + (mt*16 + ln15)*72 + kt2*32 + ln4*8);

    // one-hot precompute: ohw[rt][kt][half] byte u = 1<<(cm_byte - w*8) if in-range.
    unsigned ohw[4][2][2];
    {
        const unsigned w8 = (unsigned)(w * 8);
        #pragma unroll
        for (int rt = 0; rt < 4; ++rt)
            #pragma unroll
            for (int kt = 0; kt < 2; ++kt) {
                const unsigned* cp = (const unsigned*)(cm + (rt*16 + ln15)*64 + kt*32 + ln4*8);
                #pragma unroll
                for (int hh = 0; hh < 2; ++hh) {
                    unsigned cw = cp[hh], oh = 0u;
                    #pragma unroll
                    for (int u = 0; u < 4; ++u) {
                        unsigned d = ((cw >> (8*u)) & 255u) - w8;   // wraps huge if byte<w8
                        if (d < 8u) oh |= (1u << d) << (8*u);
                    }
                    ohw[rt][kt][hh] = oh;
                }
            }
    }

    f32x4 acc[4][4];                    // [rt][nt]
    #pragma unroll
    for (int rt = 0; rt < 4; ++rt)
        #pragma unroll
        for (int nt = 0; nt < 4; ++nt) acc[rt][nt] = (f32x4){0.f,0.f,0.f,0.f};

    auto load_cell = [&](short8 (&bw)[2][4], int cidx) {
        const int g = w*8 + ((cidx + xph) & 7);
        const short* wg = Wt + (size_t)g*4096;
        #pragma unroll
        for (int kt = 0; kt < 2; ++kt)
            #pragma unroll
            for (int nt = 0; nt < 4; ++nt)
                bw[kt][nt] = *(const short8*)(wg + (nt*16 + ln15)*64 + kt*32 + ln4*8);
    };
    auto compute_cell = [&](const short8 (&bw)[2][4], int cidx) {
        const int c2 = (cidx + xph) & 7;            // wave-uniform bit index
        #pragma unroll
        for (int rt = 0; rt < 4; ++rt) {
            short8 sf[2];
            #pragma unroll
            for (int kt = 0; kt < 2; ++kt) {
                unsigned t0 = (ohw[rt][kt][0] >> c2) & 0x01010101u;  // e0..e3 flags
                unsigned t1 = (ohw[rt][kt][1] >> c2) & 0x01010101u;  // e4..e7 flags
                union { unsigned u[4]; short8 s; } sfu;
                // disjoint-bit pack (verified R10..R18)
                sfu.u[0] = ((t0 & 1u)          | ((t0 << 8) & 0x10000u)) * 0x3F80u; // e0,e1
                sfu.u[1] = (((t0 >> 16) & 1u)  | ((t0 >> 8) & 0x10000u)) * 0x3F80u; // e2,e3
                sfu.u[2] = ((t1 & 1u)          | ((t1 << 8) & 0x10000u)) * 0x3F80u; // e4,e5
                sfu.u[3] = (((t1 >> 16) & 1u)  | ((t1 >> 8) & 0x10000u)) * 0x3F80u; // e6,e7
                sf[kt] = sfu.s;
            }
            f32x4 pt[4];
            #pragma unroll
            for (int mt = 0; mt < 4; ++mt) pt[mt] = (f32x4){0.f,0.f,0.f,0.f};
            #pragma unroll
            for (int kt2 = 0; kt2 < 2; ++kt2)
                #pragma unroll
                for (int mt = 0; mt < 4; ++mt)
                    pt[mt] = __builtin_amdgcn_mfma_f32_16x16x32_bf16(hf2[mt][kt2], sf[kt2], pt[mt], 0, 0, 0);
            #pragma unroll
            for (int kt = 0; kt < 2; ++kt) {
                short8 af;
                #pragma unroll
                for (int r = 0; r < 4; ++r) {
                    af[r]     = (short)f2b(pt[2*kt    ][r]);
                    af[4 + r] = (short)f2b(pt[2*kt + 1][r]);
                }
                #pragma unroll
                for (int nt = 0; nt < 4; ++nt)
                    acc[rt][nt] = __builtin_amdgcn_mfma_f32_16x16x32_bf16(af, bw[kt][nt], acc[rt][nt], 0, 0, 0);
            }
        }
    };

    // software-pipelined cell loop: prefetch next cell's Wt frags during compute
    short8 bwA[2][4], bwB[2][4];
    load_cell(bwA, 0);
    #pragma unroll
    for (int cc = 0; cc < 8; cc += 2) {
        if (cc + 1 < 8) load_cell(bwB, cc + 1);
        compute_cell(bwA, cc);
        if (cc + 2 < 8) load_cell(bwA, cc + 2);
        if (cc + 1 < 8) compute_cell(bwB, cc + 1);
    }
    __syncthreads();                                 // staging reads all hoisted

    // 4-step two-buffer combine: waves 0-3 -> Xs0, waves 4-7 -> Xs1 (parallel)
    float* Xs0 = (float*)smem;
    float* Xs1 = (float*)(smem + SM_XS1);
    for (int step = 0; step < 4; ++step) {
        if ((w & 3) == step) {
            float* Xs = (w < 4) ? Xs0 : Xs1;
            #pragma unroll
            for (int rt = 0; rt < 4; ++rt)
                #pragma unroll
                for (int nt = 0; nt < 4; ++nt)
                    #pragma unroll
                    for (int r = 0; r < 4; ++r) {
                        int row = rt*16 + ln4*4 + r; // C/D: col=lane&15, row=(lane>>4)*4+reg
                        int col = nt*16 + ln15;
                        if (step == 0) Xs[row*68 + col]  = acc[rt][nt][r];
                        else           Xs[row*68 + col] += acc[rt][nt][r];
                    }
        }
        __syncthreads();
    }

    // write X + bias (f32x4 coalesced): 512 threads x 8 floats
    {
        const int row = tid >> 3, c0 = (tid & 7)*8;
        float* xg = X + (size_t)(base + row)*64 + c0;
        #pragma unroll
        for (int q = 0; q < 2; ++q) {
            f32x4 v;
            #pragma unroll
            for (int u = 0; u < 4; ++u) {
                int o = row*68 + c0 + q*4 + u;
                v[u] = Xs0[o] + Xs1[o] + bvec[c0 + q*4 + u];
            }
            *(f32x4*)(xg + q*4) = v;
        }
    }

    // per-block column sum / sumsq (with bias) over 64 rows -> sharded atomic stats
    {
        float* red1 = (float*)(smem + SM_RED);       // [4][64]
        float* red2 = red1 + 256;
        if (tid < 256) {
            int col = tid & 63, rg = tid >> 6;
            float bc = bvec[col], s1 = 0.f, s2 = 0.f;
            for (int ii = 0; ii < 16; ++ii) {
                int o = (rg*16 + ii)*68 + col;
                float xv = Xs0[o] + Xs1[o] + bc;
                s1 += xv; s2 += xv*xv;
            }
            red1[rg*64 + col] = s1;
            red2[rg*64 + col] = s2;
        }
        __syncthreads();
        if (tid < 128) {
            int hs = tid >> 6, c2 = tid & 63;
            const float* r0 = hs ? red2 : red1;
            float v = r0[c2] + r0[64 + c2] + r0[128 + c2] + r0[192 + c2];
            atomicAdd(statbuf + (b & 15)*128 + tid, v);  // 16-way sharded
        }
    }
}

// ---------------- K2: read sharded stats + normalize + ReLU ----------------
__global__ __launch_bounds__(256) void sp_finish(
    float* __restrict__ X, const float* __restrict__ statbuf,
    const float* __restrict__ gamma, const float* __restrict__ beta)
{
    __shared__ float scale[64], shift[64];
    const int b = blockIdx.x, tid = threadIdx.x;

    if (tid < 64) {
        const float inv_n = 1.0f / (float)NTOT;
        float s1 = 0.f, s2 = 0.f;
        #pragma unroll
        for (int s = 0; s < 16; ++s) {
            s1 += statbuf[s*128 + tid];
            s2 += statbuf[s*128 + 64 + tid];
        }
        float mu  = s1 * inv_n;
        float var = s2 * inv_n - mu*mu;
        float sc  = gamma[tid] / sqrtf(var + EPSV);
        scale[tid] = sc;
        shift[tid] = beta[tid] - mu*sc;
    }
    __syncthreads();
    #pragma unroll
    for (int q = 0; q < 4; ++q) {
        size_t idx4 = (size_t)b*1024 + q*256 + tid;  // f32x4 units
        f32x4 v = ((f32x4*)X)[idx4];
        int c0 = ((int)idx4*4) & 63;
        #pragma unroll
        for (int u = 0; u < 4; ++u)
            v[u] = fmaxf(v[u]*scale[c0 + u] + shift[c0 + u], 0.0f);
        ((f32x4*)X)[idx4] = v;
    }
}

extern "C" void kernel_launch(void* const* d_in, const int* in_sizes, int n_in,
                              void* d_out, int out_size, void* d_ws, size_t ws_size,
                              hipStream_t stream)
{
    const float* h     = (const float*)d_in[0];
    // d_in[1] seq_start_end: provably uniform (reference only uses N//nseq)
    const float* pos   = (const float*)d_in[2];
    const float* W     = (const float*)d_in[3];
    const float* bvec  = (const float*)d_in[4];
    const float* gamma = (const float*)d_in[5];
    const float* beta  = (const float*)d_in[6];

    float* X       = (float*)d_out;
    short* Wt      = (short*)d_ws;                   // 512 KB bf16 W' (k-permuted)
    float* statbuf = (float*)((char*)d_ws + 524288); // 16*128 floats: sharded stats

    sp_transpose<<<64,   256, 0, stream>>>(W, Wt, statbuf);
    sp_main     <<<NSEQ, 512, 0, stream>>>(h, pos, Wt, bvec, X, statbuf);
    sp_finish   <<<NSEQ, 256, 0, stream>>>(X, statbuf, gamma, beta);
}